// Round 5
// baseline (759.376 us; speedup 1.0000x reference)
//
#include <hip/hip_runtime.h>
#include <hip/hip_cooperative_groups.h>
#include <math.h>

namespace cg = cooperative_groups;

#define B 32
#define N 16384
#define M 128
#define D 1024
#define L 390   // 3*M+6
#define EPSF 1e-16f

#define GRID  1024
#define BPB   (GRID / B)        // 32 blocks per batch
#define CHUNK (N / BPB)         // 512 rows per block

// ws layout (floats):
//   [O_OFF,  O_OFF+B*L)   o = emb@W + b
//   [S1_OFF, +B)          sum exp(z)   (atomic; zeroed by k1)
//   [S2_OFF, +B)          sum w_sh     (atomic; zeroed by k1)
//   [Z_OFF,  +B*N)        u = exp(beta*sim)
#define O_OFF  0
#define S1_OFF (B*L)
#define S2_OFF (S1_OFF + B)
#define Z_OFF  (S2_OFF + B)

typedef float fvec4 __attribute__((ext_vector_type(4)));

__device__ __forceinline__ float softplusf(float x) {
    return x > 20.f ? x : log1pf(expf(x));
}
__device__ __forceinline__ float sigmoidf(float x) {
    return 1.f / (1.f + expf(-x));
}

// K1: o[b, l0:l0+64] = emb[b,:] @ W[:, l0:l0+64] + bias.  grid(7, B), 256 thr.
// Block x==0 also zeroes the S1/S2 accumulators for its batch.
__global__ __launch_bounds__(256) void k1_gemm(const float* __restrict__ emb,
                                               const float* __restrict__ W,
                                               const float* __restrict__ bias,
                                               float* __restrict__ ws) {
    __shared__ float embS[D];
    __shared__ float red[4][64];
    const int l0 = blockIdx.x * 64;
    const int b  = blockIdx.y;
    const int t  = threadIdx.x;
    for (int i = t; i < D; i += 256) embS[i] = emb[b * D + i];
    if (blockIdx.x == 0 && t == 0) {
        ws[S1_OFF + b] = 0.f;
        ws[S2_OFF + b] = 0.f;
    }
    __syncthreads();
    const int li = t & 63;
    const int q  = t >> 6;          // 4-way split of the D dimension
    const int l  = l0 + li;
    float partial = 0.f;
    if (l < L) {
        const float* wp = W + (size_t)(q * 256) * L + l;
        #pragma unroll 8
        for (int d = 0; d < 256; ++d) partial += embS[q * 256 + d] * wp[(size_t)d * L];
    }
    red[q][li] = partial;
    __syncthreads();
    if (t < 64 && l0 + t < L) {
        float o = red[0][t] + red[1][t] + red[2][t] + red[3][t] + bias[l0 + t];
        ws[O_OFF + b * L + l0 + t] = o;
    }
}

// ===========================================================================
// K234: fused cooperative kernel = k2 (sim+S1) | sync | k3 (shift+S2) |
// sync | k4 (finalize+write). 1024 blocks x 256 thr, 4 blocks/CU.
// Each block owns batch b = blk/32, rows [n0, n0+512).
// Phase bodies are verbatim the proven round-3/4 implementations.
// ===========================================================================
__global__ __launch_bounds__(256, 4) void k234(const float* __restrict__ w_prev,
                                               const float* __restrict__ mem,
                                               float* __restrict__ ws,
                                               float* __restrict__ out) {
    cg::grid_group gg = cg::this_grid();
    const int t    = threadIdx.x;
    const int wave = t >> 6, lane = t & 63;
    const int blk  = blockIdx.x;
    const int b    = blk / BPB;
    const int n0   = (blk % BPB) * CHUNK;
    __shared__ float kS[M];
    __shared__ float par[8];
    __shared__ float acc[4];
    const float* o = ws + O_OFF + b * L;

    // ---- Phase A (k2): u[n] = exp(beta*cos_sim(mem[n],k)); S1 += sum ----
    if (t < M) kS[t] = o[t];
    __syncthreads();
    if (t < M) {                               // local ||k||
        float kv = kS[t];
        float sq = kv * kv;
        #pragma unroll
        for (int off = 32; off >= 1; off >>= 1) sq += __shfl_xor(sq, off, 64);
        if (lane == 0) acc[t >> 6] = sq;
    }
    __syncthreads();
    if (t == 0) {
        par[0] = sqrtf(acc[0] + acc[1]);
        par[1] = softplusf(o[M]);
    }
    __syncthreads();
    {
        const float knorm = par[0], beta = par[1];
        float s1sum = 0.f;
        #pragma unroll
        for (int h = 0; h < CHUNK / 256; ++h) {
            const int n = n0 + h * 256 + t;    // row-per-lane
            const float* mp = mem + ((size_t)b * N + n) * M;
            float dot = 0.f, sq = 0.f;
            #pragma unroll 16
            for (int j = 0; j < M / 4; ++j) {
                const fvec4 mv = *(const fvec4*)(mp + j * 4);
                const fvec4 kv = *(const fvec4*)&kS[j * 4];
                dot = fmaf(mv.x, kv.x, dot); dot = fmaf(mv.y, kv.y, dot);
                dot = fmaf(mv.z, kv.z, dot); dot = fmaf(mv.w, kv.w, dot);
                sq  = fmaf(mv.x, mv.x, sq);  sq  = fmaf(mv.y, mv.y, sq);
                sq  = fmaf(mv.z, mv.z, sq);  sq  = fmaf(mv.w, mv.w, sq);
            }
            const float sim = dot / (sqrtf(sq) * knorm + EPSF);
            const float uu  = expf(beta * sim);
            ws[Z_OFF + (size_t)b * N + n] = uu;
            s1sum += uu;
        }
        #pragma unroll
        for (int off = 32; off >= 1; off >>= 1) s1sum += __shfl_xor(s1sum, off, 64);
        if (lane == 0) acc[wave] = s1sum;
        __syncthreads();
        if (t == 0) atomicAdd(ws + S1_OFF + b, acc[0] + acc[1] + acc[2] + acc[3]);
    }
    gg.sync();

    // ---- Phase B (k3): w_sh = (s·wg neighborhood)^gamma; S2 += sum ----
    if (t == 0) {
        par[2] = sigmoidf(o[M + 1]);
        float x0 = o[M + 2], x1 = o[M + 3], x2 = o[M + 4];
        float mx = fmaxf(x0, fmaxf(x1, x2));
        float e0 = expf(x0 - mx), e1 = expf(x1 - mx), e2 = expf(x2 - mx);
        float inv = 1.f / (e0 + e1 + e2);
        par[3] = e0 * inv; par[4] = e1 * inv; par[5] = e2 * inv;
        par[6] = 1.f + softplusf(o[M + 5]);
        par[7] = 1.f / ws[S1_OFF + b];
    }
    __syncthreads();
    {
        const float g = par[2], s0 = par[3], s1v = par[4], s2v = par[5];
        const float gamma = par[6], invS1 = par[7];
        const float gm1 = 1.f - g, gi = g * invS1;
        const float* u  = ws + Z_OFF + (size_t)b * N;
        const float* wp = w_prev + (size_t)b * N;
        float s2sum = 0.f;
        #pragma unroll
        for (int h = 0; h < CHUNK / 256; ++h) {
            const int n  = n0 + h * 256 + t;
            const int nm = (n == 0)     ? N - 1 : n - 1;
            const int np = (n == N - 1) ? 0     : n + 1;
            const float wgm = gi * u[nm] + gm1 * wp[nm];
            const float wg0 = gi * u[n ] + gm1 * wp[n ];
            const float wgp = gi * u[np] + gm1 * wp[np];
            const float wt  = s0 * wgm + s1v * wg0 + s2v * wgp;
            const float v = powf(wt, gamma);
            out[(size_t)b * N + n] = v;        // stash w_sh
            s2sum += v;
        }
        #pragma unroll
        for (int off = 32; off >= 1; off >>= 1) s2sum += __shfl_xor(s2sum, off, 64);
        __syncthreads();                       // acc reuse
        if (lane == 0) acc[wave] = s2sum;
        __syncthreads();
        if (t == 0) atomicAdd(ws + S2_OFF + b, acc[0] + acc[1] + acc[2] + acc[3]);
    }
    gg.sync();

    // ---- Phase C (k4): wv = w_sh*invS2; new_mem = mem*(1-wv*e)+wv*a ----
    __shared__ float eS[M], aS[M];
    if (t < M) {
        eS[t] = sigmoidf(o[M + 6 + t]);
        aS[t] = o[2 * M + 6 + t];
    }
    __syncthreads();
    {
        const float invS2 = 1.f / (ws[S2_OFF + b] + EPSF);
        float* w_out = out + (size_t)b * N;
        float* m_out = out + (size_t)B * N;
        const int col  = (lane & 31) * 4;
        const int half = lane >> 5;
        const fvec4 ev = *(const fvec4*)&eS[col];
        const fvec4 av = *(const fvec4*)&aS[col];
        #pragma unroll
        for (int tile = 0; tile < CHUNK / 64; ++tile) {
            const int base = n0 + tile * 64 + wave * 16;
            float wv[8];                       // preload before any store
            #pragma unroll
            for (int it = 0; it < 8; ++it)
                wv[it] = w_out[base + it * 2 + half] * invS2;
            #pragma unroll
            for (int it = 0; it < 8; ++it) {
                const int n = base + it * 2 + half;
                const size_t idx = ((size_t)b * N + n) * M + col;
                const fvec4 mv = *(const fvec4*)(mem + idx);   // L3-hot from phase A
                const float w = wv[it];
                fvec4 r;
                r.x = fmaf(mv.x, fmaf(-w, ev.x, 1.f), w * av.x);
                r.y = fmaf(mv.y, fmaf(-w, ev.y, 1.f), w * av.y);
                r.z = fmaf(mv.z, fmaf(-w, ev.z, 1.f), w * av.z);
                r.w = fmaf(mv.w, fmaf(-w, ev.w, 1.f), w * av.w);
                __builtin_nontemporal_store(r, (fvec4*)(m_out + idx));
            }
            if ((lane & 31) == 0) {
                #pragma unroll
                for (int it = 0; it < 8; ++it)
                    w_out[base + it * 2 + half] = wv[it];
            }
        }
    }
}

// ===========================================================================
// Fallback split kernels (proven round-4 path) in case coop launch fails.
// ===========================================================================
__global__ __launch_bounds__(256) void k2_sim(const float* __restrict__ mem,
                                              float* __restrict__ ws) {
    const int b = blockIdx.y;
    const int t = threadIdx.x;
    const int n = blockIdx.x * 256 + t;
    const int wave = t >> 6, lane = t & 63;
    __shared__ float kS[M];
    __shared__ float par[2];
    __shared__ float acc[4];
    const float* o = ws + O_OFF + b * L;
    if (t < M) kS[t] = o[t];
    __syncthreads();
    if (t < M) {
        float kv = kS[t];
        float sq = kv * kv;
        #pragma unroll
        for (int off = 32; off >= 1; off >>= 1) sq += __shfl_xor(sq, off, 64);
        if (lane == 0) acc[t >> 6] = sq;
    }
    __syncthreads();
    if (t == 0) {
        par[0] = sqrtf(acc[0] + acc[1]);
        par[1] = softplusf(o[M]);
    }
    __syncthreads();
    const float knorm = par[0], beta = par[1];
    const float* mp = mem + ((size_t)b * N + n) * M;
    float dot = 0.f, sq = 0.f;
    #pragma unroll 16
    for (int j = 0; j < M / 4; ++j) {
        const fvec4 mv = *(const fvec4*)(mp + j * 4);
        const fvec4 kv = *(const fvec4*)&kS[j * 4];
        dot = fmaf(mv.x, kv.x, dot); dot = fmaf(mv.y, kv.y, dot);
        dot = fmaf(mv.z, kv.z, dot); dot = fmaf(mv.w, kv.w, dot);
        sq  = fmaf(mv.x, mv.x, sq);  sq  = fmaf(mv.y, mv.y, sq);
        sq  = fmaf(mv.z, mv.z, sq);  sq  = fmaf(mv.w, mv.w, sq);
    }
    const float sim = dot / (sqrtf(sq) * knorm + EPSF);
    const float uu  = expf(beta * sim);
    ws[Z_OFF + (size_t)b * N + n] = uu;
    float r = uu;
    #pragma unroll
    for (int off = 32; off >= 1; off >>= 1) r += __shfl_xor(r, off, 64);
    if (lane == 0) acc[wave] = r;
    __syncthreads();
    if (t == 0) atomicAdd(ws + S1_OFF + b, acc[0] + acc[1] + acc[2] + acc[3]);
}

__global__ __launch_bounds__(256) void k3_shsum(const float* __restrict__ w_prev,
                                                float* __restrict__ ws,
                                                float* __restrict__ out) {
    const int b = blockIdx.y;
    const int n = blockIdx.x * 256 + threadIdx.x;
    __shared__ float par[6];
    if (threadIdx.x == 0) {
        const float* o = ws + O_OFF + b * L;
        par[0] = sigmoidf(o[M + 1]);
        float x0 = o[M + 2], x1 = o[M + 3], x2 = o[M + 4];
        float mx = fmaxf(x0, fmaxf(x1, x2));
        float e0 = expf(x0 - mx), e1 = expf(x1 - mx), e2 = expf(x2 - mx);
        float inv = 1.f / (e0 + e1 + e2);
        par[1] = e0 * inv; par[2] = e1 * inv; par[3] = e2 * inv;
        par[4] = 1.f + softplusf(o[M + 5]);
        par[5] = 1.f / ws[S1_OFF + b];
    }
    __syncthreads();
    const float g = par[0], s0 = par[1], s1 = par[2], s2 = par[3];
    const float gamma = par[4], invS1 = par[5];
    const float* u  = ws + Z_OFF + (size_t)b * N;
    const float* wp = w_prev + (size_t)b * N;
    const int nm = (n == 0)     ? N - 1 : n - 1;
    const int np = (n == N - 1) ? 0     : n + 1;
    const float gm1 = 1.f - g;
    const float gi  = g * invS1;
    const float wgm = gi * u[nm] + gm1 * wp[nm];
    const float wg0 = gi * u[n ] + gm1 * wp[n ];
    const float wgp = gi * u[np] + gm1 * wp[np];
    const float wt  = s0 * wgm + s1 * wg0 + s2 * wgp;
    const float v = powf(wt, gamma);
    out[(size_t)b * N + n] = v;
    float r = v;
    #pragma unroll
    for (int off = 32; off >= 1; off >>= 1) r += __shfl_xor(r, off, 64);
    __shared__ float acc[4];
    if ((threadIdx.x & 63) == 0) acc[threadIdx.x >> 6] = r;
    __syncthreads();
    if (threadIdx.x == 0) atomicAdd(ws + S2_OFF + b, acc[0] + acc[1] + acc[2] + acc[3]);
}

__global__ __launch_bounds__(256) void k4_write(const float* __restrict__ mem,
                                                const float* __restrict__ ws,
                                                float* __restrict__ out) {
    const int b    = blockIdx.y;
    const int n0   = (gridDim.x - 1 - blockIdx.x) * 64;
    const int t    = threadIdx.x;
    const int wave = t >> 6, lane = t & 63;
    __shared__ float eS[M], aS[M];
    if (t < M) {
        eS[t] = sigmoidf(ws[O_OFF + b * L + M + 6 + t]);
        aS[t] = ws[O_OFF + b * L + 2 * M + 6 + t];
    }
    __syncthreads();
    const float invS2 = 1.f / (ws[S2_OFF + b] + EPSF);
    float* w_out = out + (size_t)b * N;
    float* m_out = out + (size_t)B * N;
    const int col  = (lane & 31) * 4;
    const int half = lane >> 5;
    const int base = n0 + wave * 16;
    const fvec4 ev = *(const fvec4*)&eS[col];
    const fvec4 av = *(const fvec4*)&aS[col];
    float wv[8];
    #pragma unroll
    for (int it = 0; it < 8; ++it)
        wv[it] = w_out[base + it * 2 + half] * invS2;
    #pragma unroll
    for (int it = 0; it < 8; ++it) {
        const int n = base + it * 2 + half;
        const size_t idx = ((size_t)b * N + n) * M + col;
        const fvec4 mv = *(const fvec4*)(mem + idx);
        const float w = wv[it];
        fvec4 r;
        r.x = fmaf(mv.x, fmaf(-w, ev.x, 1.f), w * av.x);
        r.y = fmaf(mv.y, fmaf(-w, ev.y, 1.f), w * av.y);
        r.z = fmaf(mv.z, fmaf(-w, ev.z, 1.f), w * av.z);
        r.w = fmaf(mv.w, fmaf(-w, ev.w, 1.f), w * av.w);
        __builtin_nontemporal_store(r, (fvec4*)(m_out + idx));
    }
    if ((lane & 31) == 0) {
        #pragma unroll
        for (int it = 0; it < 8; ++it)
            w_out[base + it * 2 + half] = wv[it];
    }
}

extern "C" void kernel_launch(void* const* d_in, const int* in_sizes, int n_in,
                              void* d_out, int out_size, void* d_ws, size_t ws_size,
                              hipStream_t stream) {
    const float* emb    = (const float*)d_in[0];
    const float* w_prev = (const float*)d_in[1];
    const float* mem    = (const float*)d_in[2];
    const float* W      = (const float*)d_in[3];
    const float* bias   = (const float*)d_in[4];
    float* ws  = (float*)d_ws;    // needs (B*L + 2*B + B*N)*4 ≈ 2.15 MB
    float* out = (float*)d_out;

    k1_gemm<<<dim3(7, B), 256, 0, stream>>>(emb, W, bias, ws);

    void* args[] = {(void*)&w_prev, (void*)&mem, (void*)&ws, (void*)&out};
    hipError_t err = hipLaunchCooperativeKernel((const void*)k234,
                                                dim3(GRID), dim3(256),
                                                args, 0, stream);
    if (err != hipSuccess) {
        k2_sim  <<<dim3(N / 256, B), 256, 0, stream>>>(mem, ws);
        k3_shsum<<<dim3(N / 256, B), 256, 0, stream>>>(w_prev, ws, out);
        k4_write<<<dim3(N / 64, B),  256, 0, stream>>>(mem, ws, out);
    }
}

// Round 6
// 552.119 us; speedup vs baseline: 1.3754x; 1.3754x over previous
//
#include <hip/hip_runtime.h>
#include <math.h>

#define B 32
#define N 16384
#define M 128
#define D 1024
#define L 390   // 3*M+6
#define EPSF 1e-16f

// ws layout (floats):
//   [O_OFF,  O_OFF+B*L)   o = emb@W + b
//   [S1_OFF, +B)          sum exp(z)   (atomic; zeroed by k1)
//   [S2_OFF, +B)          sum w_sh     (atomic; zeroed by k1)
//   [Z_OFF,  +B*N)        u = exp(beta*sim)
// Per-batch params are recomputed locally per block from o (k1b removed).
// w_sh no longer round-trips through `out`: k3 is a pure S2 reduction and
// k4 recomputes w per block (identical arithmetic -> identical values).
#define O_OFF  0
#define S1_OFF (B*L)
#define S2_OFF (S1_OFF + B)
#define Z_OFF  (S2_OFF + B)

typedef float fvec4 __attribute__((ext_vector_type(4)));

__device__ __forceinline__ float softplusf(float x) {
    return x > 20.f ? x : log1pf(expf(x));
}
__device__ __forceinline__ float sigmoidf(float x) {
    return 1.f / (1.f + expf(-x));
}

// K1: o[b, l0:l0+64] = emb[b,:] @ W[:, l0:l0+64] + bias.  grid(7, B), 256 thr.
// Block x==0 also zeroes the S1/S2 accumulators for its batch.
__global__ __launch_bounds__(256) void k1_gemm(const float* __restrict__ emb,
                                               const float* __restrict__ W,
                                               const float* __restrict__ bias,
                                               float* __restrict__ ws) {
    __shared__ float embS[D];
    __shared__ float red[4][64];
    const int l0 = blockIdx.x * 64;
    const int b  = blockIdx.y;
    const int t  = threadIdx.x;
    for (int i = t; i < D; i += 256) embS[i] = emb[b * D + i];
    if (blockIdx.x == 0 && t == 0) {
        ws[S1_OFF + b] = 0.f;
        ws[S2_OFF + b] = 0.f;
    }
    __syncthreads();
    const int li = t & 63;
    const int q  = t >> 6;          // 4-way split of the D dimension
    const int l  = l0 + li;
    float partial = 0.f;
    if (l < L) {
        const float* wp = W + (size_t)(q * 256) * L + l;
        #pragma unroll 8
        for (int d = 0; d < 256; ++d) partial += embS[q * 256 + d] * wp[(size_t)d * L];
    }
    red[q][li] = partial;
    __syncthreads();
    if (t < 64 && l0 + t < L) {
        float o = red[0][t] + red[1][t] + red[2][t] + red[3][t] + bias[l0 + t];
        ws[O_OFF + b * L + l0 + t] = o;
    }
}

// K2: u[b,n] = exp(beta*cos_sim(mem[b,n,:],k)); atomic S1 += sum u.
// COALESCED 16-lane groups: lane reads mem[row, (lane&15)*8 ..+8) -> each
// VMEM instr touches 16 cache lines (vs 64 for row-per-lane strided), easing
// the L1/TA request pipe. 4 rows per wave-iter, 4 iters -> 64 rows/block.
// knorm/beta computed locally per block. grid(N/64, B), 256 thr.
__global__ __launch_bounds__(256) void k2_sim(const float* __restrict__ mem,
                                              float* __restrict__ ws) {
    const int b    = blockIdx.y;
    const int n0   = blockIdx.x * 64;
    const int t    = threadIdx.x;
    const int wave = t >> 6, lane = t & 63;
    __shared__ float kS[M];
    __shared__ float par[2];        // {knorm, beta}
    __shared__ float acc[4];
    const float* o = ws + O_OFF + b * L;
    if (t < M) kS[t] = o[t];
    __syncthreads();
    if (t < M) {                               // local ||k||
        float kv = kS[t];
        float sq = kv * kv;
        #pragma unroll
        for (int off = 32; off >= 1; off >>= 1) sq += __shfl_xor(sq, off, 64);
        if (lane == 0) acc[t >> 6] = sq;
    }
    __syncthreads();
    if (t == 0) {
        par[0] = sqrtf(acc[0] + acc[1]);
        par[1] = softplusf(o[M]);
    }
    __syncthreads();
    const float knorm = par[0], beta = par[1];
    float* z = ws + Z_OFF + (size_t)b * N;
    const int seg = (lane & 15) * 8;           // this lane's 8-elem segment of M
    const fvec4 ka = *(const fvec4*)&kS[seg];
    const fvec4 kb = *(const fvec4*)&kS[seg + 4];
    float lsum = 0.f;
    #pragma unroll
    for (int it = 0; it < 4; ++it) {
        const int n = n0 + wave * 16 + it * 4 + (lane >> 4);
        const float* mp = mem + ((size_t)b * N + n) * M + seg;
        const fvec4 ma = *(const fvec4*)mp;
        const fvec4 mb = *(const fvec4*)(mp + 4);
        float dot = ma.x*ka.x + ma.y*ka.y + ma.z*ka.z + ma.w*ka.w
                  + mb.x*kb.x + mb.y*kb.y + mb.z*kb.z + mb.w*kb.w;
        float sq  = ma.x*ma.x + ma.y*ma.y + ma.z*ma.z + ma.w*ma.w
                  + mb.x*mb.x + mb.y*mb.y + mb.z*mb.z + mb.w*mb.w;
        #pragma unroll
        for (int off = 1; off <= 8; off <<= 1) {   // reduce within 16-lane group
            dot += __shfl_xor(dot, off, 64);
            sq  += __shfl_xor(sq,  off, 64);
        }
        // after butterfly all 16 lanes hold the result: compute uniformly,
        // only the group leader stores/accumulates.
        const float sim = dot / (sqrtf(sq) * knorm + EPSF);
        const float uu  = expf(beta * sim);
        if ((lane & 15) == 0) {
            z[n] = uu;
            lsum += uu;
        }
    }
    lsum += __shfl_xor(lsum, 16, 64);          // gather leaders 0,16,32,48
    lsum += __shfl_xor(lsum, 32, 64);
    if (lane == 0) acc[wave] = lsum;
    __syncthreads();
    if (t == 0) atomicAdd(ws + S1_OFF + b, acc[0] + acc[1] + acc[2] + acc[3]);
}

// K3: PURE S2 reduction: S2 += sum_n (s0*wg(n-1)+s1*wg(n)+s2*wg(n+1))^gamma.
// No w_sh store (k4 recomputes identically). grid(N/256, B), 256 thr.
__global__ __launch_bounds__(256) void k3_s2(const float* __restrict__ w_prev,
                                             float* __restrict__ ws) {
    const int b = blockIdx.y;
    const int n = blockIdx.x * 256 + threadIdx.x;
    __shared__ float par[6];        // {g, s0, s1, s2, gamma, invS1}
    if (threadIdx.x == 0) {
        const float* o = ws + O_OFF + b * L;
        par[0] = sigmoidf(o[M + 1]);
        float x0 = o[M + 2], x1 = o[M + 3], x2 = o[M + 4];
        float mx = fmaxf(x0, fmaxf(x1, x2));
        float e0 = expf(x0 - mx), e1 = expf(x1 - mx), e2 = expf(x2 - mx);
        float inv = 1.f / (e0 + e1 + e2);
        par[1] = e0 * inv; par[2] = e1 * inv; par[3] = e2 * inv;
        par[4] = 1.f + softplusf(o[M + 5]);
        par[5] = 1.f / ws[S1_OFF + b];
    }
    __syncthreads();
    const float g = par[0], s0 = par[1], s1 = par[2], s2 = par[3];
    const float gamma = par[4], invS1 = par[5];
    const float* u  = ws + Z_OFF + (size_t)b * N;
    const float* wp = w_prev + (size_t)b * N;
    const int nm = (n == 0)     ? N - 1 : n - 1;
    const int np = (n == N - 1) ? 0     : n + 1;
    const float gm1 = 1.f - g;
    const float gi  = g * invS1;
    const float wgm = gi * u[nm] + gm1 * wp[nm];
    const float wg0 = gi * u[n ] + gm1 * wp[n ];
    const float wgp = gi * u[np] + gm1 * wp[np];
    const float wt  = s0 * wgm + s1 * wg0 + s2 * wgp;
    const float v = powf(wt, gamma);
    float r = v;
    #pragma unroll
    for (int off = 32; off >= 1; off >>= 1) r += __shfl_xor(r, off, 64);
    __shared__ float acc[4];
    if ((threadIdx.x & 63) == 0) acc[threadIdx.x >> 6] = r;
    __syncthreads();
    if (threadIdx.x == 0) atomicAdd(ws + S2_OFF + b, acc[0] + acc[1] + acc[2] + acc[3]);
}

// K4: per-block prologue recomputes w for its 64 rows (identical arithmetic
// to k3 -> identical values) into LDS + one coalesced w store; main loop is
// then pure streaming with ZERO loads from its own store target:
// new_mem = mem*(1-w*e) + w*a, NT stores, reversed traversal for L3 LRU.
// grid(N/64, B), 256 thr = 4 waves, 16 rows/wave.
__global__ __launch_bounds__(256) void k4_write(const float* __restrict__ mem,
                                                const float* __restrict__ w_prev,
                                                const float* __restrict__ ws,
                                                float* __restrict__ out) {
    const int b    = blockIdx.y;
    const int n0   = (gridDim.x - 1 - blockIdx.x) * 64;   // reversed traversal
    const int t    = threadIdx.x;
    const int wave = t >> 6, lane = t & 63;
    __shared__ float eS[M], aS[M], wS[64];
    __shared__ float par[8];
    const float* o = ws + O_OFF + b * L;
    if (t < M) {
        eS[t] = sigmoidf(o[M + 6 + t]);
        aS[t] = o[2 * M + 6 + t];
    }
    if (t == 0) {
        par[0] = sigmoidf(o[M + 1]);
        float x0 = o[M + 2], x1 = o[M + 3], x2 = o[M + 4];
        float mx = fmaxf(x0, fmaxf(x1, x2));
        float e0 = expf(x0 - mx), e1 = expf(x1 - mx), e2 = expf(x2 - mx);
        float inv = 1.f / (e0 + e1 + e2);
        par[1] = e0 * inv; par[2] = e1 * inv; par[3] = e2 * inv;
        par[4] = 1.f + softplusf(o[M + 5]);
        par[5] = 1.f / ws[S1_OFF + b];
        par[6] = 1.f / (ws[S2_OFF + b] + EPSF);
    }
    __syncthreads();
    if (t < 64) {                              // w for this block's 64 rows
        const int n  = n0 + t;
        const float g = par[0], s0 = par[1], s1v = par[2], s2v = par[3];
        const float gamma = par[4], invS1 = par[5], invS2 = par[6];
        const float gi = g * invS1, gm1 = 1.f - g;
        const float* u  = ws + Z_OFF + (size_t)b * N;
        const float* wp = w_prev + (size_t)b * N;
        const int nm = (n == 0)     ? N - 1 : n - 1;
        const int np = (n == N - 1) ? 0     : n + 1;
        const float wgm = gi * u[nm] + gm1 * wp[nm];
        const float wg0 = gi * u[n ] + gm1 * wp[n ];
        const float wgp = gi * u[np] + gm1 * wp[np];
        const float wt  = s0 * wgm + s1v * wg0 + s2v * wgp;
        const float wv  = powf(wt, gamma) * invS2;
        wS[t] = wv;
        out[(size_t)b * N + n] = wv;           // coalesced 64-lane w store
    }
    __syncthreads();
    float* m_out = out + (size_t)B * N;
    const int col  = (lane & 31) * 4;
    const int half = lane >> 5;
    const fvec4 ev = *(const fvec4*)&eS[col];
    const fvec4 av = *(const fvec4*)&aS[col];
    #pragma unroll
    for (int it = 0; it < 8; ++it) {
        const int loc = wave * 16 + it * 2 + half;
        const int n   = n0 + loc;
        const float w = wS[loc];               // LDS broadcast
        const size_t idx = ((size_t)b * N + n) * M + col;
        const fvec4 mv = *(const fvec4*)(mem + idx);   // L3-hot from k2
        fvec4 r;
        r.x = fmaf(mv.x, fmaf(-w, ev.x, 1.f), w * av.x);
        r.y = fmaf(mv.y, fmaf(-w, ev.y, 1.f), w * av.y);
        r.z = fmaf(mv.z, fmaf(-w, ev.z, 1.f), w * av.z);
        r.w = fmaf(mv.w, fmaf(-w, ev.w, 1.f), w * av.w);
        __builtin_nontemporal_store(r, (fvec4*)(m_out + idx));
    }
}

extern "C" void kernel_launch(void* const* d_in, const int* in_sizes, int n_in,
                              void* d_out, int out_size, void* d_ws, size_t ws_size,
                              hipStream_t stream) {
    const float* emb    = (const float*)d_in[0];
    const float* w_prev = (const float*)d_in[1];
    const float* mem    = (const float*)d_in[2];
    const float* W      = (const float*)d_in[3];
    const float* bias   = (const float*)d_in[4];
    float* ws  = (float*)d_ws;    // needs (B*L + 2*B + B*N)*4 ≈ 2.15 MB
    float* out = (float*)d_out;

    k1_gemm <<<dim3(7, B),       256, 0, stream>>>(emb, W, bias, ws);
    k2_sim  <<<dim3(N / 64, B),  256, 0, stream>>>(mem, ws);
    k3_s2   <<<dim3(N / 256, B), 256, 0, stream>>>(w_prev, ws);
    k4_write<<<dim3(N / 64, B),  256, 0, stream>>>(mem, w_prev, ws, out);
}

// Round 7
// 536.958 us; speedup vs baseline: 1.4142x; 1.0282x over previous
//
#include <hip/hip_runtime.h>
#include <math.h>

#define B 32
#define N 16384
#define M 128
#define D 1024
#define L 390   // 3*M+6
#define EPSF 1e-16f

// ws layout (floats):
//   [O_OFF,  O_OFF+B*L)   o = emb@W + b
//   [S1_OFF, +B)          sum exp(z)   (atomic; zeroed by k1)
//   [S2_OFF, +B)          sum w_sh     (atomic; zeroed by k1)
//   [Z_OFF,  +B*N)        u = exp(beta*sim)
// Per-batch params are recomputed locally per block from o.
// w_sh does not round-trip through `out`: k3 is a pure S2 reduction and
// k4 recomputes w per block (identical arithmetic -> identical values).
#define O_OFF  0
#define S1_OFF (B*L)
#define S2_OFF (S1_OFF + B)
#define Z_OFF  (S2_OFF + B)

typedef float fvec4 __attribute__((ext_vector_type(4)));

__device__ __forceinline__ float softplusf(float x) {
    return x > 20.f ? x : log1pf(expf(x));
}
__device__ __forceinline__ float sigmoidf(float x) {
    return 1.f / (1.f + expf(-x));
}

// K1: o[b, l0:l0+64] = emb[b,:] @ W[:, l0:l0+64] + bias.  grid(7, B), 256 thr.
// Block x==0 also zeroes the S1/S2 accumulators for its batch.
__global__ __launch_bounds__(256) void k1_gemm(const float* __restrict__ emb,
                                               const float* __restrict__ W,
                                               const float* __restrict__ bias,
                                               float* __restrict__ ws) {
    __shared__ float embS[D];
    __shared__ float red[4][64];
    const int l0 = blockIdx.x * 64;
    const int b  = blockIdx.y;
    const int t  = threadIdx.x;
    for (int i = t; i < D; i += 256) embS[i] = emb[b * D + i];
    if (blockIdx.x == 0 && t == 0) {
        ws[S1_OFF + b] = 0.f;
        ws[S2_OFF + b] = 0.f;
    }
    __syncthreads();
    const int li = t & 63;
    const int q  = t >> 6;          // 4-way split of the D dimension
    const int l  = l0 + li;
    float partial = 0.f;
    if (l < L) {
        const float* wp = W + (size_t)(q * 256) * L + l;
        #pragma unroll 8
        for (int d = 0; d < 256; ++d) partial += embS[q * 256 + d] * wp[(size_t)d * L];
    }
    red[q][li] = partial;
    __syncthreads();
    if (t < 64 && l0 + t < L) {
        float o = red[0][t] + red[1][t] + red[2][t] + red[3][t] + bias[l0 + t];
        ws[O_OFF + b * L + l0 + t] = o;
    }
}

// K2: u[b,n] = exp(beta*cos_sim(mem[b,n,:],k)); atomic S1 += sum u.
// ROW-PER-LANE (proven fastest, R3/R4): each lane owns one full row
// (32 x float4 independent sequential loads, k broadcast from LDS).
// No cross-lane ops or divergence in the hot loop; u store wave-coalesced.
// knorm/beta computed locally per block. grid(N/256, B), 256 thr.
__global__ __launch_bounds__(256) void k2_sim(const float* __restrict__ mem,
                                              float* __restrict__ ws) {
    const int b = blockIdx.y;
    const int t = threadIdx.x;
    const int n = blockIdx.x * 256 + t;
    const int wave = t >> 6, lane = t & 63;
    __shared__ float kS[M];
    __shared__ float par[2];        // {knorm, beta}
    __shared__ float acc[4];
    const float* o = ws + O_OFF + b * L;
    if (t < M) kS[t] = o[t];
    __syncthreads();
    if (t < M) {                               // local ||k||
        float kv = kS[t];
        float sq = kv * kv;
        #pragma unroll
        for (int off = 32; off >= 1; off >>= 1) sq += __shfl_xor(sq, off, 64);
        if (lane == 0) acc[t >> 6] = sq;
    }
    __syncthreads();
    if (t == 0) {
        par[0] = sqrtf(acc[0] + acc[1]);
        par[1] = softplusf(o[M]);
    }
    __syncthreads();
    const float knorm = par[0], beta = par[1];
    const float* mp = mem + ((size_t)b * N + n) * M;

    float dot = 0.f, sq = 0.f;
    #pragma unroll 16
    for (int j = 0; j < M / 4; ++j) {
        const fvec4 mv = *(const fvec4*)(mp + j * 4);
        const fvec4 kv = *(const fvec4*)&kS[j * 4];     // LDS broadcast
        dot = fmaf(mv.x, kv.x, dot); dot = fmaf(mv.y, kv.y, dot);
        dot = fmaf(mv.z, kv.z, dot); dot = fmaf(mv.w, kv.w, dot);
        sq  = fmaf(mv.x, mv.x, sq);  sq  = fmaf(mv.y, mv.y, sq);
        sq  = fmaf(mv.z, mv.z, sq);  sq  = fmaf(mv.w, mv.w, sq);
    }
    const float sim = dot / (sqrtf(sq) * knorm + EPSF);
    const float uu  = expf(beta * sim);
    ws[Z_OFF + (size_t)b * N + n] = uu;        // fully coalesced store

    float r = uu;                              // block reduction -> S1
    #pragma unroll
    for (int off = 32; off >= 1; off >>= 1) r += __shfl_xor(r, off, 64);
    if (lane == 0) acc[wave] = r;
    __syncthreads();
    if (t == 0) atomicAdd(ws + S1_OFF + b, acc[0] + acc[1] + acc[2] + acc[3]);
}

// K3: PURE S2 reduction: S2 += sum_n (s0*wg(n-1)+s1*wg(n)+s2*wg(n+1))^gamma.
// No w_sh store (k4 recomputes identically). grid(N/256, B), 256 thr.
__global__ __launch_bounds__(256) void k3_s2(const float* __restrict__ w_prev,
                                             float* __restrict__ ws) {
    const int b = blockIdx.y;
    const int n = blockIdx.x * 256 + threadIdx.x;
    __shared__ float par[6];        // {g, s0, s1, s2, gamma, invS1}
    if (threadIdx.x == 0) {
        const float* o = ws + O_OFF + b * L;
        par[0] = sigmoidf(o[M + 1]);
        float x0 = o[M + 2], x1 = o[M + 3], x2 = o[M + 4];
        float mx = fmaxf(x0, fmaxf(x1, x2));
        float e0 = expf(x0 - mx), e1 = expf(x1 - mx), e2 = expf(x2 - mx);
        float inv = 1.f / (e0 + e1 + e2);
        par[1] = e0 * inv; par[2] = e1 * inv; par[3] = e2 * inv;
        par[4] = 1.f + softplusf(o[M + 5]);
        par[5] = 1.f / ws[S1_OFF + b];
    }
    __syncthreads();
    const float g = par[0], s0 = par[1], s1 = par[2], s2 = par[3];
    const float gamma = par[4], invS1 = par[5];
    const float* u  = ws + Z_OFF + (size_t)b * N;
    const float* wp = w_prev + (size_t)b * N;
    const int nm = (n == 0)     ? N - 1 : n - 1;
    const int np = (n == N - 1) ? 0     : n + 1;
    const float gm1 = 1.f - g;
    const float gi  = g * invS1;
    const float wgm = gi * u[nm] + gm1 * wp[nm];
    const float wg0 = gi * u[n ] + gm1 * wp[n ];
    const float wgp = gi * u[np] + gm1 * wp[np];
    const float wt  = s0 * wgm + s1 * wg0 + s2 * wgp;
    const float v = powf(wt, gamma);
    float r = v;
    #pragma unroll
    for (int off = 32; off >= 1; off >>= 1) r += __shfl_xor(r, off, 64);
    __shared__ float acc[4];
    if ((threadIdx.x & 63) == 0) acc[threadIdx.x >> 6] = r;
    __syncthreads();
    if (threadIdx.x == 0) atomicAdd(ws + S2_OFF + b, acc[0] + acc[1] + acc[2] + acc[3]);
}

// K4: per-block prologue recomputes w for its 64 rows (identical arithmetic
// to k3 -> identical values) into LDS + one coalesced w store; main loop is
// then pure streaming with ZERO loads from its own store target:
// new_mem = mem*(1-w*e) + w*a, NT stores, reversed traversal for L3 LRU.
// grid(N/64, B), 256 thr = 4 waves, 16 rows/wave.
__global__ __launch_bounds__(256) void k4_write(const float* __restrict__ mem,
                                                const float* __restrict__ w_prev,
                                                const float* __restrict__ ws,
                                                float* __restrict__ out) {
    const int b    = blockIdx.y;
    const int n0   = (gridDim.x - 1 - blockIdx.x) * 64;   // reversed traversal
    const int t    = threadIdx.x;
    const int wave = t >> 6, lane = t & 63;
    __shared__ float eS[M], aS[M], wS[64];
    __shared__ float par[8];
    const float* o = ws + O_OFF + b * L;
    if (t < M) {
        eS[t] = sigmoidf(o[M + 6 + t]);
        aS[t] = o[2 * M + 6 + t];
    }
    if (t == 0) {
        par[0] = sigmoidf(o[M + 1]);
        float x0 = o[M + 2], x1 = o[M + 3], x2 = o[M + 4];
        float mx = fmaxf(x0, fmaxf(x1, x2));
        float e0 = expf(x0 - mx), e1 = expf(x1 - mx), e2 = expf(x2 - mx);
        float inv = 1.f / (e0 + e1 + e2);
        par[1] = e0 * inv; par[2] = e1 * inv; par[3] = e2 * inv;
        par[4] = 1.f + softplusf(o[M + 5]);
        par[5] = 1.f / ws[S1_OFF + b];
        par[6] = 1.f / (ws[S2_OFF + b] + EPSF);
    }
    __syncthreads();
    if (t < 64) {                              // w for this block's 64 rows
        const int n  = n0 + t;
        const float g = par[0], s0 = par[1], s1v = par[2], s2v = par[3];
        const float gamma = par[4], invS1 = par[5], invS2 = par[6];
        const float gi = g * invS1, gm1 = 1.f - g;
        const float* u  = ws + Z_OFF + (size_t)b * N;
        const float* wp = w_prev + (size_t)b * N;
        const int nm = (n == 0)     ? N - 1 : n - 1;
        const int np = (n == N - 1) ? 0     : n + 1;
        const float wgm = gi * u[nm] + gm1 * wp[nm];
        const float wg0 = gi * u[n ] + gm1 * wp[n ];
        const float wgp = gi * u[np] + gm1 * wp[np];
        const float wt  = s0 * wgm + s1v * wg0 + s2v * wgp;
        const float wv  = powf(wt, gamma) * invS2;
        wS[t] = wv;
        out[(size_t)b * N + n] = wv;           // coalesced 64-lane w store
    }
    __syncthreads();
    float* m_out = out + (size_t)B * N;
    const int col  = (lane & 31) * 4;
    const int half = lane >> 5;
    const fvec4 ev = *(const fvec4*)&eS[col];
    const fvec4 av = *(const fvec4*)&aS[col];
    #pragma unroll
    for (int it = 0; it < 8; ++it) {
        const int loc = wave * 16 + it * 2 + half;
        const int n   = n0 + loc;
        const float w = wS[loc];               // LDS broadcast
        const size_t idx = ((size_t)b * N + n) * M + col;
        const fvec4 mv = *(const fvec4*)(mem + idx);   // L3-hot from k2
        fvec4 r;
        r.x = fmaf(mv.x, fmaf(-w, ev.x, 1.f), w * av.x);
        r.y = fmaf(mv.y, fmaf(-w, ev.y, 1.f), w * av.y);
        r.z = fmaf(mv.z, fmaf(-w, ev.z, 1.f), w * av.z);
        r.w = fmaf(mv.w, fmaf(-w, ev.w, 1.f), w * av.w);
        __builtin_nontemporal_store(r, (fvec4*)(m_out + idx));
    }
}

extern "C" void kernel_launch(void* const* d_in, const int* in_sizes, int n_in,
                              void* d_out, int out_size, void* d_ws, size_t ws_size,
                              hipStream_t stream) {
    const float* emb    = (const float*)d_in[0];
    const float* w_prev = (const float*)d_in[1];
    const float* mem    = (const float*)d_in[2];
    const float* W      = (const float*)d_in[3];
    const float* bias   = (const float*)d_in[4];
    float* ws  = (float*)d_ws;    // needs (B*L + 2*B + B*N)*4 ≈ 2.15 MB
    float* out = (float*)d_out;

    k1_gemm <<<dim3(7, B),       256, 0, stream>>>(emb, W, bias, ws);
    k2_sim  <<<dim3(N / 256, B), 256, 0, stream>>>(mem, ws);
    k3_s2   <<<dim3(N / 256, B), 256, 0, stream>>>(w_prev, ws);
    k4_write<<<dim3(N / 64, B),  256, 0, stream>>>(mem, w_prev, ws, out);
}